// Round 3
// baseline (15750.285 us; speedup 1.0000x reference)
//
#include <hip/hip_runtime.h>
#include <hip/hip_bf16.h>

typedef __hip_bfloat16 bf16;

#define NBATCH 128
#define TT 128
#define VV 19
#define NT (NBATCH*TT)
#define EPSF 1e-5f

static __device__ __forceinline__ float b2f(bf16 v){ return __bfloat162float(v); }
static __device__ __forceinline__ bf16  f2b(float v){ return __float2bfloat16(v); }
// dual-dtype input load: mode=1 -> fp32, mode=0 -> bf16
static __device__ __forceinline__ float ldi(const void* p, size_t i, int mode){
  return mode ? ((const float*)p)[i] : b2f(((const bf16*)p)[i]);
}

// acc[0..18] += w * row[0..18]; row is 16B-aligned, 20 floats long (pad)
static __device__ __forceinline__ void fma19(float* acc, float w, const float* row){
  const float4* r = (const float4*)row;
  float4 a=r[0], b=r[1], c=r[2], d=r[3], e=r[4];
  acc[0]+=w*a.x;  acc[1]+=w*a.y;  acc[2]+=w*a.z;  acc[3]+=w*a.w;
  acc[4]+=w*b.x;  acc[5]+=w*b.y;  acc[6]+=w*b.z;  acc[7]+=w*b.w;
  acc[8]+=w*c.x;  acc[9]+=w*c.y;  acc[10]+=w*c.z; acc[11]+=w*c.w;
  acc[12]+=w*d.x; acc[13]+=w*d.y; acc[14]+=w*d.z; acc[15]+=w*d.w;
  acc[16]+=w*e.x; acc[17]+=w*e.y; acc[18]+=w*e.z;
}

// ---- detect input dtype: fp32 buffers read as bf16 have wild exponents ----
__global__ void k_detect(const unsigned short* __restrict__ p, int* __restrict__ flag){
  const int tid = threadIdx.x;
  __shared__ int cnt;
  if(tid==0) cnt = 0;
  __syncthreads();
  int local = 0;
  for(int i=tid; i<2048; i+=256){
    unsigned short h = p[i];
    int e = (h>>7) & 0xFF;                 // bf16 exponent field
    if(h != 0 && (e < 107 || e > 147)) local++;   // |v| outside ~[2^-20, 2^20]
  }
  atomicAdd(&cnt, local);
  __syncthreads();
  if(tid==0) *flag = (cnt > 300) ? 1 : 0;
}

// ---- canary: pre-fill output with 3.0 (overwritten by stage3 if pipeline completes) ----
__global__ void k_canary(void* __restrict__ out, int n, const int* __restrict__ flag){
  int i = blockIdx.x*256 + threadIdx.x;
  if(i >= n) return;
  if(*flag) ((float*)out)[i] = 3.0f;
  else      ((bf16*)out)[i]  = f2b(3.0f);
}

__global__ void k_zero(float* __restrict__ p, int n){
  int i = blockIdx.x*256 + threadIdx.x;
  if(i < n) p[i] = 0.f;
}

// ---- fmv = tanh(fm)+1 ----
__global__ void k_tanhp1(const void* __restrict__ fm, float* __restrict__ out, int n,
                         const int* __restrict__ flag){
  int i = blockIdx.x*256 + threadIdx.x;
  int mode = *flag;
  if(i < n) out[i] = tanhf(ldi(fm, i, mode)) + 1.0f;
}

// ---- g = softmax( A @ B ) per (n,t) ----
__global__ __launch_bounds__(256)
void k_gspa(const void* __restrict__ x0,
            const void* __restrict__ w1, const void* __restrict__ b1,
            const void* __restrict__ w2, const void* __restrict__ b2,
            float* __restrict__ gout, const int* __restrict__ flag)
{
  const int s = blockIdx.x;
  const int n = s / TT, t = s % TT;
  const int tid = threadIdx.x;
  const int mode = *flag;
  __shared__ float xt[64][20];
  __shared__ float Am[VV][32];
  __shared__ float Bm[32][20];
  __shared__ float Sm[VV][20];
  for(int idx=tid; idx<64*VV; idx+=256){
    int c = idx/VV, u = idx - c*VV;
    xt[c][u] = ldi(x0, (((size_t)n*64 + c)*TT + t)*VV + u, mode);
  }
  __syncthreads();
  for(int idx=tid; idx<VV*32; idx+=256){
    int u = idx/32, k = idx & 31;
    float acc = ldi(b1, k, mode);
    for(int c=0;c<64;c++) acc += xt[c][u]*ldi(w1, k*64+c, mode);
    Am[u][k] = acc;
  }
  for(int idx=tid; idx<32*VV; idx+=256){
    int k = idx/VV, w = idx - k*VV;
    float acc = ldi(b2, k, mode);
    for(int c=0;c<64;c++) acc += xt[c][w]*ldi(w2, k*64+c, mode);
    Bm[k][w] = acc;
  }
  __syncthreads();
  for(int idx=tid; idx<VV*VV; idx+=256){
    int u = idx/VV, w = idx - u*VV;
    float acc = 0.f;
#pragma unroll
    for(int k=0;k<32;k++) acc += Am[u][k]*Bm[k][w];
    Sm[u][w] = acc;
  }
  __syncthreads();
  if(tid < VV){
    int u = tid;
    float mx = -1e30f;
    for(int w=0;w<VV;w++) mx = fmaxf(mx, Sm[u][w]);
    float sum = 0.f;
    for(int w=0;w<VV;w++){ float e = __expf(Sm[u][w]-mx); Sm[u][w]=e; sum+=e; }
    float r = 1.0f/sum;
    for(int w=0;w<VV;w++) Sm[u][w] *= r;
  }
  __syncthreads();
  float* gp = gout + (size_t)s*(VV*VV);
  for(int idx=tid; idx<VV*VV; idx+=256) gp[idx] = Sm[idx/VV][idx%VV];
}

// ---- Stage 1: ypre[i][d] = sum_j xs[i][j]*lw[j][d] ----
// PREV: input is previous block's y in zbuf layout, apply BN2d(A2p,B2p)+relu on load.
template<int CIN_, int COUT_, bool DOWN, bool PREV>
__global__ __launch_bounds__(256)
void k_stage1(const void* __restrict__ xin,
              const float* __restrict__ A2p, const float* __restrict__ B2p,
              const float* __restrict__ fmv,
              const void* __restrict__ lw, const void* __restrict__ lb,
              bf16* __restrict__ zbuf,
              const void* __restrict__ dw, const void* __restrict__ db,
              float* __restrict__ dpart, const int* __restrict__ flag)
{
  constexpr int NS = 256/COUT_;
  constexpr int JC = CIN_/NS;
  const int s = blockIdx.x;
  const int n = s / TT, t = s % TT;
  const int tid = threadIdx.x;
  const int mode = *flag;
  __shared__ __align__(16) float xt[CIN_][20];
  __shared__ __align__(16) float xsT[CIN_][20];   // xsT[j][i]
  __shared__ float pbuf[(NS-1)*COUT_*VV];
  __shared__ float ds1[256], ds2[256];

  if constexpr (PREV){
    const bf16* zin = (const bf16*)xin + (size_t)s*(CIN_*VV);
    for(int idx=tid; idx<CIN_*VV; idx+=256){
      int c = idx/VV, u = idx - c*VV;
      xt[c][u] = fmaxf(b2f(zin[idx])*A2p[c] + B2p[c], 0.f);
    }
  } else {
    for(int idx=tid; idx<CIN_*VV; idx+=256){
      int c = idx/VV, u = idx - c*VV;
      xt[c][u] = ldi(xin, (((size_t)n*CIN_ + c)*TT + t)*VV + u, mode);
    }
  }
  __syncthreads();
  for(int idx=tid; idx<CIN_*VV; idx+=256){
    int j = idx/VV, i = idx - j*VV;
    xsT[j][i] = xt[j][(i+j)%VV] * fmv[i*CIN_ + j];
  }
  __syncthreads();

  const int d  = tid % COUT_;
  const int sp = tid / COUT_;
  float acc[VV];
#pragma unroll
  for(int i=0;i<VV;i++) acc[i]=0.f;
  for(int j=sp*JC; j<(sp+1)*JC; j++){
    float lwv = ldi(lw, j*COUT_ + d, mode);
    fma19(acc, lwv, xsT[j]);
  }
  if(sp > 0){
#pragma unroll
    for(int i=0;i<VV;i++) pbuf[((sp-1)*COUT_+d)*VV + i] = acc[i];
  }
  __syncthreads();
  if(sp == 0){
    float lbv = ldi(lb, d, mode);
    bf16* zp = zbuf + (size_t)s*(VV*COUT_);
#pragma unroll
    for(int i=0;i<VV;i++){
      float v = acc[i] + lbv;
#pragma unroll
      for(int q=1;q<NS;q++) v += pbuf[((q-1)*COUT_+d)*VV + i];
      zp[i*COUT_ + d] = f2b(v);
    }
  }
  if constexpr (DOWN){
    const int oc  = tid & 127;
    const int grp = tid >> 7;
    float a1=0.f, a2=0.f;
    for(int u=grp; u<VV; u+=2){
      float r = ldi(db, oc, mode);
      for(int c=0;c<CIN_;c++) r += ldi(dw, oc*CIN_ + c, mode) * xt[c][u];
      a1 += r; a2 += r*r;
    }
    ds1[tid]=a1; ds2[tid]=a2;
    __syncthreads();
    if(tid < 128){
      float* bucket = dpart + (size_t)(s & 63)*256;
      atomicAdd(&bucket[tid],       ds1[tid] + ds1[tid+128]);
      atomicAdd(&bucket[128 + tid], ds2[tid] + ds2[tid+128]);
    }
  }
}

// ---- column stats of [NT][F] bf16 buffer ----
__global__ __launch_bounds__(256)
void k_colstats(const bf16* __restrict__ zb, int F,
                float* __restrict__ s1, float* __restrict__ s2)
{
  int f = blockIdx.x*256 + threadIdx.x;
  if(f >= F) return;
  const int RP = NT/64;
  const bf16* p = zb + (size_t)(blockIdx.y*RP)*F + f;
  float a=0.f, b=0.f;
  for(int r=0; r<RP; r++){ float v = b2f(p[(size_t)r*F]); a += v; b += v*v; }
  atomicAdd(&s1[f], a);
  atomicAdd(&s2[f], b);
}

// ---- BN1d finalize with shift-out folded into index mapping ----
template<int COUT_>
__global__ void k_fin1(const float* __restrict__ s1, const float* __restrict__ s2,
                       const void* __restrict__ bng, const void* __restrict__ bnb,
                       float* __restrict__ A1, float* __restrict__ B1,
                       const int* __restrict__ flag)
{
  const int F = VV*COUT_;
  int fp = blockIdx.x*256 + threadIdx.x;
  if(fp >= F) return;
  int mode = *flag;
  int ip = fp/COUT_, d = fp - ip*COUT_;
  int f = ((ip + d)%VV)*COUT_ + d;        // post-shift feature
  float m = s1[fp] * (1.0f/NT);
  float v = s2[fp] * (1.0f/NT) - m*m;
  float a = ldi(bng, f, mode) * rsqrtf(v + EPSF);
  A1[fp] = a;
  B1[fp] = ldi(bnb, f, mode) - m*a;
}

// ---- BN2d finalize (per channel over (sample,u)) ----
template<int COUT_>
__global__ void k_fin2(const float* __restrict__ s1, const float* __restrict__ s2,
                       const void* __restrict__ bnsg, const void* __restrict__ bnsb,
                       float* __restrict__ A2, float* __restrict__ B2,
                       const int* __restrict__ flag)
{
  int d = threadIdx.x;
  if(d >= COUT_) return;
  int mode = *flag;
  float a=0.f, b=0.f;
  for(int u=0;u<VV;u++){ a += s1[d*VV+u]; b += s2[d*VV+u]; }
  const float inv = 1.0f/((float)NT*VV);
  float m = a*inv, v = b*inv - m*m;
  float g_ = ldi(bnsg, d, mode) * rsqrtf(v + EPSF);
  A2[d] = g_;
  B2[d] = ldi(bnsb, d, mode) - m*g_;
}

// ---- reduce 64 buckets -> A2d/B2d for the down-path BN ----
__global__ void k_dfin(const float* __restrict__ dpart, const void* __restrict__ dbng,
                       const void* __restrict__ dbnb, float* __restrict__ A2d,
                       float* __restrict__ B2d, const int* __restrict__ flag){
  int c = threadIdx.x;           // 256 threads: c<128 -> sum, c>=128 -> sumsq
  int mode = *flag;
  float a = 0.f;
  for(int r=0;r<64;r++) a += dpart[(size_t)r*256 + c];
  __shared__ float red[256];
  red[c] = a;
  __syncthreads();
  if(c < 128){
    const float inv = 1.0f/((float)NT*VV);
    float m = red[c]*inv;
    float v = red[128+c]*inv - m*m;
    float g_ = ldi(dbng, c, mode) * rsqrtf(v + EPSF);
    A2d[c] = g_;
    B2d[c] = ldi(dbnb, c, mode) - m*g_;
  }
}

// ---- Stage 2: BN1d + residual + ReLU, graph matmul, output convs -> y (in-place in zy) ----
template<int CIN_, int COUT_, bool DOWN, bool PREV>
__global__ __launch_bounds__(256)
void k_stage2(const void* __restrict__ xin,
              const float* __restrict__ A2p, const float* __restrict__ B2p,
              bf16* __restrict__ zy,
              const float* __restrict__ A1, const float* __restrict__ B1,
              const float* __restrict__ gmat,
              const void* __restrict__ ww, const void* __restrict__ w1w,
              const void* __restrict__ w1b,
              const void* __restrict__ dw, const void* __restrict__ db,
              const float* __restrict__ A2d, const float* __restrict__ B2d,
              const int* __restrict__ flag)
{
  constexpr int NS = 256/COUT_;
  constexpr int F  = VV*COUT_;
  constexpr int CC = COUT_/NS;
  const int s = blockIdx.x;
  const int n = s/TT, t = s % TT;
  const int tid = threadIdx.x;
  const int mode = *flag;
  __shared__ __align__(16) float X2[COUT_][20];   // [channel][node]
  __shared__ __align__(16) float XG[COUT_][20];
  __shared__ __align__(16) float XT[CIN_][20];
  __shared__ float gt[VV][20];
  __shared__ float comb[(NS-1)*COUT_*VV];

  if constexpr (PREV){
    const bf16* zin = (const bf16*)xin + (size_t)s*(CIN_*VV);
    for(int idx=tid; idx<CIN_*VV; idx+=256){
      int c = idx/VV, u = idx - c*VV;
      XT[c][u] = fmaxf(b2f(zin[idx])*A2p[c] + B2p[c], 0.f);
    }
  } else {
    for(int idx=tid; idx<CIN_*VV; idx+=256){
      int c = idx/VV, u = idx - c*VV;
      XT[c][u] = ldi(xin, (((size_t)n*CIN_ + c)*TT + t)*VV + u, mode);
    }
  }
  for(int idx=tid; idx<VV*VV; idx+=256)
    gt[idx/VV][idx%VV] = gmat[(size_t)s*(VV*VV) + idx];
  __syncthreads();

  bf16* zp = zy + (size_t)s*F;
  for(int idx=tid; idx<F; idx+=256){
    int ip = idx/COUT_, d = idx - ip*COUT_;
    int u = (ip + d) % VV;
    float res;
    if constexpr (DOWN){
      float r = ldi(db, d, mode);
      for(int c=0;c<CIN_;c++) r += ldi(dw, d*CIN_ + c, mode) * XT[c][u];
      res = r*A2d[d] + B2d[d];
    } else {
      res = XT[d][u];
    }
    float v = b2f(zp[idx])*A1[idx] + B1[idx] + res;
    X2[d][u] = fmaxf(v, 0.f);
  }
  __syncthreads();
  for(int idx=tid; idx<F; idx+=256){
    int c = idx/VV, u = idx - c*VV;
    float acc = 0.f;
#pragma unroll
    for(int w=0; w<VV; w++) acc += gt[u][w]*X2[c][w];
    XG[c][u] = acc;
  }
  __syncthreads();
  const int d  = tid % COUT_;
  const int sp = tid / COUT_;
  float acc[VV];
#pragma unroll
  for(int i=0;i<VV;i++) acc[i]=0.f;
  for(int c=sp*CC; c<(sp+1)*CC; c++){
    float wwv = ldi(ww,  d*COUT_ + c, mode);
    float w1v = ldi(w1w, d*COUT_ + c, mode);
    fma19(acc, wwv, XG[c]);
    fma19(acc, w1v, X2[c]);
  }
  if(sp > 0){
#pragma unroll
    for(int i=0;i<VV;i++) comb[((sp-1)*COUT_+d)*VV + i] = acc[i];
  }
  __syncthreads();
  if(sp == 0){
    float bv = ldi(w1b, d, mode);
#pragma unroll
    for(int i=0;i<VV;i++){
      float v = acc[i] + bv;
#pragma unroll
      for(int q=1;q<NS;q++) v += comb[((q-1)*COUT_+d)*VV + i];
      zp[d*VV + i] = f2b(v);
    }
  }
}

// ---- Stage 3 (final only): BN2d + ReLU -> output [n][d][t][u]; NaN canary ----
template<int COUT_>
__global__ __launch_bounds__(256)
void k_stage3(const bf16* __restrict__ ybuf, const float* __restrict__ A2,
              const float* __restrict__ B2, void* __restrict__ out,
              const int* __restrict__ flag)
{
  const int s = blockIdx.x, n = s/TT, t = s % TT, tid = threadIdx.x;
  const int mode = *flag;
  constexpr int F = VV*COUT_;
  const bf16* yp = ybuf + (size_t)s*F;
  for(int idx=tid; idx<F; idx+=256){
    int d = idx/VV, u = idx - d*VV;
    float v0 = b2f(yp[idx])*A2[d] + B2[d];
    float v = fmaxf(v0, 0.f);
    if(!(v0 == v0) || fabsf(v0) > 1e30f) v = 1000.0f;   // NaN/Inf canary
    size_t o = (((size_t)n*COUT_ + d)*TT + t)*VV + u;
    if(mode) ((float*)out)[o] = v;
    else     ((bf16*)out)[o]  = f2b(v);
  }
}

extern "C" void kernel_launch(void* const* d_in, const int* in_sizes, int n_in,
                              void* d_out, int out_size, void* d_ws, size_t ws_size,
                              hipStream_t stream)
{
  const void* in[39];
  for(int i=0;i<39;i++) in[i] = d_in[i];

  char* ws = (char*)d_ws;
  size_t off = 0;
  auto alloc = [&](size_t bytes)->void*{
    void* p = ws + off;
    off = (off + bytes + 255) & ~(size_t)255;
    return p;
  };
  int*   flag = (int*)  alloc(4);
  float* gmat = (float*)alloc((size_t)NT*VV*VV*4);      // 23.7 MB
  bf16*  zA   = (bf16*) alloc((size_t)NT*2432*2);       // 79.7 MB
  bf16*  zB   = (bf16*) alloc((size_t)NT*2432*2);       // 79.7 MB
  float* dpart= (float*)alloc((size_t)64*256*4);        // 64 KB
  float* s1   = (float*)alloc(2432*4);
  float* s2   = (float*)alloc(2432*4);
  float* A1   = (float*)alloc(2432*4);
  float* B1   = (float*)alloc(2432*4);
  float* A2b1 = (float*)alloc(128*4);
  float* B2b1 = (float*)alloc(128*4);
  float* A2b2 = (float*)alloc(128*4);
  float* B2b2 = (float*)alloc(128*4);
  float* A2b3 = (float*)alloc(128*4);
  float* B2b3 = (float*)alloc(128*4);
  float* A2d  = (float*)alloc(128*4);
  float* B2d  = (float*)alloc(128*4);
  float* fmv1 = (float*)alloc(1216*4);
  float* fmv2 = (float*)alloc(1216*4);
  float* fmv3 = (float*)alloc(2432*4);

  if(ws_size < off){
    // workspace too small sentinel: fill out with ~12.06 (bf16 0x4141 pattern)
    hipMemsetAsync(d_out, 0x41, (size_t)out_size*2, stream);
    return;
  }

  k_detect<<<1,256,0,stream>>>((const unsigned short*)in[0], flag);
  k_canary<<<(out_size+255)/256,256,0,stream>>>(d_out, out_size, flag);

  k_tanhp1<<<5,256,0,stream>>>(in[7],  fmv1, 1216, flag);
  k_tanhp1<<<5,256,0,stream>>>(in[17], fmv2, 1216, flag);
  k_tanhp1<<<10,256,0,stream>>>(in[31], fmv3, 2432, flag);
  k_gspa<<<NT,256,0,stream>>>(in[0], in[1], in[2], in[3], in[4], gmat, flag);

  // ---- Block 1 (64 -> 64, identity residual), input = x0, ypre/y in zA ----
  k_stage1<64,64,false,false><<<NT,256,0,stream>>>(in[0], nullptr, nullptr, fmv1,
                                                   in[5], in[6], zA,
                                                   nullptr, nullptr, nullptr, flag);
  k_zero<<<19,256,0,stream>>>(s1, 2*2432);   // s1,s2 contiguous
  k_colstats<<<dim3(5,64),256,0,stream>>>(zA, 1216, s1, s2);
  k_fin1<64><<<5,256,0,stream>>>(s1, s2, in[8], in[9], A1, B1, flag);
  k_stage2<64,64,false,false><<<NT,256,0,stream>>>(in[0], nullptr, nullptr, zA, A1, B1,
                                                   gmat, in[12], in[13], in[14],
                                                   nullptr, nullptr, nullptr, nullptr, flag);
  k_zero<<<19,256,0,stream>>>(s1, 2*2432);
  k_colstats<<<dim3(5,64),256,0,stream>>>(zA, 1216, s1, s2);
  k_fin2<64><<<1,64,0,stream>>>(s1, s2, in[10], in[11], A2b1, B2b1, flag);

  // ---- Block 2 (64 -> 128, down path), input = BN2d(zA)+relu, ypre/y in zB ----
  k_zero<<<64,256,0,stream>>>(dpart, 64*256);
  k_stage1<64,128,true,true><<<NT,256,0,stream>>>(zA, A2b1, B2b1, fmv2,
                                                  in[15], in[16], zB,
                                                  in[25], in[26], dpart, flag);
  k_dfin<<<1,256,0,stream>>>(dpart, in[27], in[28], A2d, B2d, flag);
  k_zero<<<19,256,0,stream>>>(s1, 2*2432);
  k_colstats<<<dim3(10,64),256,0,stream>>>(zB, 2432, s1, s2);
  k_fin1<128><<<10,256,0,stream>>>(s1, s2, in[18], in[19], A1, B1, flag);
  k_stage2<64,128,true,true><<<NT,256,0,stream>>>(zA, A2b1, B2b1, zB, A1, B1,
                                                  gmat, in[22], in[23], in[24],
                                                  in[25], in[26], A2d, B2d, flag);
  k_zero<<<19,256,0,stream>>>(s1, 2*2432);
  k_colstats<<<dim3(10,64),256,0,stream>>>(zB, 2432, s1, s2);
  k_fin2<128><<<1,128,0,stream>>>(s1, s2, in[20], in[21], A2b2, B2b2, flag);

  // ---- Block 3 (128 -> 128, identity), input = BN2d(zB)+relu, ypre/y in zA ----
  k_stage1<128,128,false,true><<<NT,256,0,stream>>>(zB, A2b2, B2b2, fmv3,
                                                    in[29], in[30], zA,
                                                    nullptr, nullptr, nullptr, flag);
  k_zero<<<19,256,0,stream>>>(s1, 2*2432);
  k_colstats<<<dim3(10,64),256,0,stream>>>(zA, 2432, s1, s2);
  k_fin1<128><<<10,256,0,stream>>>(s1, s2, in[32], in[33], A1, B1, flag);
  k_stage2<128,128,false,true><<<NT,256,0,stream>>>(zB, A2b2, B2b2, zA, A1, B1,
                                                    gmat, in[36], in[37], in[38],
                                                    nullptr, nullptr, nullptr, nullptr, flag);
  k_zero<<<19,256,0,stream>>>(s1, 2*2432);
  k_colstats<<<dim3(10,64),256,0,stream>>>(zA, 2432, s1, s2);
  k_fin2<128><<<1,128,0,stream>>>(s1, s2, in[34], in[35], A2b3, B2b3, flag);
  k_stage3<128><<<NT,256,0,stream>>>(zA, A2b3, B2b3, d_out, flag);
}